// Round 1
// baseline (789.827 us; speedup 1.0000x reference)
//
#include <hip/hip_runtime.h>
#include <math.h>

#define BNUM 2
#define V0 4096
#define V1N 1024
#define V2N 256
#define SUPN 7

typedef float float4v __attribute__((ext_vector_type(4)));

__device__ __forceinline__ float fast_silu(float x){
  // x * sigmoid(x) = x / (1 + exp(-x))
  return __fdividef(x, 1.0f + __expf(-x));
}

// ---------------- column-normalize directions: (3, ncols) ----------------
__global__ void colnorm_k(const float* __restrict__ d, float* __restrict__ o, int ncols){
  int c = blockIdx.x*blockDim.x + threadIdx.x;
  if(c>=ncols) return;
  float a=d[c], b=d[ncols+c], e=d[2*ncols+c];
  float n=sqrtf(a*a+b*b+e*e); n=fmaxf(n,1e-12f);
  o[c]=a/n; o[ncols+c]=b/n; o[2*ncols+c]=e/n;
}

// ---------------- KNN / nearest: one 256-thread block per query ----------------
// cand: (B, Vc, 3). qry: (B, Vqs, 3) batch-stride Vqs. qmap: optional query row list.
// Selects (K+skip) nearest by d = |q|^2+|c|^2-2*q.c, ties -> lower index,
// drops first `skip`, writes K indices; optionally writes unit direction vectors.
__global__ __launch_bounds__(256) void knn_k(
    const float* __restrict__ cand, int Vc,
    const float* __restrict__ qry, int Vqs,
    const int* __restrict__ qmap, int K, int skip,
    int* __restrict__ out_idx, float* __restrict__ out_dirn)
{
  int b=blockIdx.y, j=blockIdx.x, t=threadIdx.x;
  int nq=gridDim.x;
  extern __shared__ float sm[];
  float* sdist=sm;            // Vc
  float* rval=sm+Vc;          // 256
  int*   ridx=(int*)(rval+256); // 256
  int*   swin=ridx+256;       // 16
  int qrow = qmap ? qmap[j] : j;
  const float* q = qry + ((size_t)b*Vqs + qrow)*3;
  float qx=q[0],qy=q[1],qz=q[2];
  float qs=qx*qx+qy*qy+qz*qz;
  const float* cb = cand + (size_t)b*Vc*3;
  for(int i=t;i<Vc;i+=256){
    float cx=cb[3*i],cy=cb[3*i+1],cz=cb[3*i+2];
    float cs=cx*cx+cy*cy+cz*cz;
    float dt=qx*cx+qy*cy+qz*cz;
    sdist[i]=qs+cs-2.0f*dt;
  }
  __syncthreads();
  int total=K+skip;
  for(int sel=0; sel<total; ++sel){
    float bv=INFINITY; int bi=0x7fffffff;
    for(int i=t;i<Vc;i+=256){
      float v=sdist[i];
      if(v<bv){bv=v;bi=i;}           // strict < keeps lowest index per thread
    }
    rval[t]=bv; ridx[t]=bi;
    __syncthreads();
    for(int s=128;s>0;s>>=1){
      if(t<s){
        float v2=rval[t+s]; int i2=ridx[t+s];
        if(v2<rval[t] || (v2==rval[t] && i2<ridx[t])){ rval[t]=v2; ridx[t]=i2; }
      }
      __syncthreads();
    }
    if(t==0){ int win=ridx[0]; swin[sel]=win; sdist[win]=INFINITY; }
    __syncthreads();
  }
  if(t>=skip && t<total){
    int win=swin[t];
    size_t obase=((size_t)b*nq+j)*K + (t-skip);
    out_idx[obase]=win;
    if(out_dirn){
      float dx=cb[3*win]-qx, dy=cb[3*win+1]-qy, dz=cb[3*win+2]-qz;
      float n=sqrtf(dx*dx+dy*dy+dz*dz); n=fmaxf(n,1e-12f);
      float* o=out_dirn + obase*3;
      o[0]=dx/n; o[1]=dy/n; o[2]=dz/n;
    }
  }
}

// ---------------- conv_surface + outer silu -> fm0 (C=128) ----------------
__global__ __launch_bounds__(128) void conv_surf_k(
    const float* __restrict__ dirn, const float* __restrict__ cnd,
    float* __restrict__ fm0)
{
  int b=blockIdx.y, i=blockIdx.x, t=threadIdx.x;
  __shared__ float sd[32];
  if(t<30) sd[t]=dirn[((size_t)(b*V0+i)*10)*3+t];
  __syncthreads();
  float acc=0.0f;
  for(int s=0;s<SUPN;s++){
    int col=s*128+t;
    float w0=cnd[col], w1c=cnd[896+col], w2c=cnd[1792+col];
    float m=-INFINITY;
    #pragma unroll
    for(int n=0;n<10;n++){
      float d=sd[3*n]*w0+sd[3*n+1]*w1c+sd[3*n+2]*w2c;
      m=fmaxf(m, fast_silu(d));
    }
    acc+=m;
  }
  fm0[(size_t)(b*V0+i)*128+t]=fast_silu(acc);
}

// ---------------- GEMM: C[M,N] = A[M,K] @ W[K,N] + bias[N] ----------------
// 64x64 tile, BK=16, 256 threads, thread computes 4x4 via float4 LDS reads.
// Requires M%64==0, N%64==0, K%16==0 (all shapes here satisfy this).
__global__ __launch_bounds__(256) void gemm_bias_k(
    const float* __restrict__ A, const float* __restrict__ Wt,
    const float* __restrict__ bias, float* __restrict__ C,
    int M, int N, int K)
{
  __shared__ float As[16][68];
  __shared__ float Bs[16][68];
  int t=threadIdx.x;
  int tx=t&15, ty=t>>4;
  int bm=blockIdx.y*64, bn=blockIdx.x*64;
  float4v acc[4];
  #pragma unroll
  for(int i=0;i<4;i++) acc[i]=(float4v)(0.0f);
  for(int k0=0;k0<K;k0+=16){
    int r=t>>4, kk=t&15;
    #pragma unroll
    for(int i=0;i<4;i++)
      As[kk][r+16*i]=A[(size_t)(bm+r+16*i)*K + (k0+kk)];
    int kw=t>>6, c=t&63;
    #pragma unroll
    for(int i=0;i<4;i++)
      Bs[kw+4*i][c]=Wt[(size_t)(k0+kw+4*i)*N + (bn+c)];
    __syncthreads();
    #pragma unroll
    for(int kk2=0;kk2<16;kk2++){
      float4v av=*(const float4v*)&As[kk2][ty*4];
      float4v bv=*(const float4v*)&Bs[kk2][tx*4];
      #pragma unroll
      for(int i=0;i<4;i++) acc[i] += av[i]*bv;
    }
    __syncthreads();
  }
  float4v biasv=*(const float4v*)&bias[bn+tx*4];
  #pragma unroll
  for(int i=0;i<4;i++){
    float4v rr=acc[i]+biasv;
    *(float4v*)&C[(size_t)(bm+ty*4+i)*N + bn+tx*4] = rr;
  }
}

// ---------------- conv_layer aggregate: out = center + sum_s max_n theta*support --------
// feat: (B*Vb, NC) with NC=8*C; blockDim = C.
__global__ void conv_agg_k(
    const float* __restrict__ feat, int Vb, int C, int NC,
    const float* __restrict__ dirn, const int* __restrict__ nbidx,
    const float* __restrict__ cnd, int ncol,
    float* __restrict__ outp)
{
  int b=blockIdx.y, i=blockIdx.x, t=threadIdx.x;
  __shared__ float sd[32]; __shared__ int snb[10];
  if(t<30) sd[t]=dirn[((size_t)(b*Vb+i)*10)*3+t];
  if(t<10) snb[t]=nbidx[(size_t)(b*Vb+i)*10+t];
  __syncthreads();
  float acc=feat[(size_t)(b*Vb+i)*NC+t];   // center
  const float* fb=feat+(size_t)b*Vb*NC;
  for(int s=0;s<SUPN;s++){
    int col=s*C+t;
    float w0=cnd[col], w1c=cnd[ncol+col], w2c=cnd[2*ncol+col];
    float m=-INFINITY;
    #pragma unroll
    for(int n=0;n<10;n++){
      float d=sd[3*n]*w0+sd[3*n+1]*w1c+sd[3*n+2]*w2c;
      float th=fast_silu(d);
      float sup=fb[(size_t)snb[n]*NC + (C+col)];
      m=fmaxf(m, th*sup);
    }
    acc+=m;
  }
  outp[(size_t)(b*Vb+i)*C+t]=acc;
}

// ---------------- BN stats: per-channel sum & sumsq via atomics ----------------
__global__ void stats_k(const float* __restrict__ xin, int chunk, int C, float* __restrict__ sums)
{
  int t=threadIdx.x;
  size_t r0=(size_t)blockIdx.x*chunk;
  float s=0.0f,s2=0.0f;
  for(int r=0;r<chunk;r++){ float v=xin[(r0+r)*C+t]; s+=v; s2+=v*v; }
  atomicAdd(&sums[t],s); atomicAdd(&sums[C+t],s2);
}

// ---------------- BN apply + silu ----------------
__global__ void bn_silu_k(const float* __restrict__ xin, const float* __restrict__ sums,
                          float invM, int C, const float* __restrict__ g, const float* __restrict__ bb,
                          float* __restrict__ y, int nelem)
{
  int gid=blockIdx.x*blockDim.x+threadIdx.x;
  if(gid>=nelem) return;
  int c=gid&(C-1);
  float mean=sums[c]*invM;
  float var=sums[C+c]*invM - mean*mean;
  float v=(xin[gid]-mean)*rsqrtf(var+1e-5f)*g[c]+bb[c];
  y[gid]=fast_silu(v);
}

// ---------------- max-pool over 4 neighbors (only at selected rows) ----------------
__global__ void pool_k(const float* __restrict__ fm, int Vsrc, int C,
                       const int* __restrict__ idx4, float* __restrict__ outp, int Vq)
{
  int b=blockIdx.y, j=blockIdx.x, t=threadIdx.x;
  const int* id=idx4+((size_t)b*Vq+j)*4;
  const float* fb=fm+(size_t)b*Vsrc*C;
  float m=-INFINITY;
  #pragma unroll
  for(int n=0;n<4;n++) m=fmaxf(m, fb[(size_t)id[n]*C+t]);
  outp[(size_t)(b*Vq+j)*C+t]=m;
}

// ---------------- gather rows (v1 = x[:,perm1], etc.) ----------------
__global__ void gather_rows_k(const float* __restrict__ src, int Vsrc, int C,
                              const int* __restrict__ perm, float* __restrict__ dst, int Vq)
{
  int b=blockIdx.y, j=blockIdx.x, t=threadIdx.x;
  if(t<C) dst[(size_t)(b*Vq+j)*C+t]=src[((size_t)b*Vsrc+perm[j])*C+t];
}

// ---------------- final concat with upsampling ----------------
__global__ __launch_bounds__(256) void concat_k(
    const float* __restrict__ fm0, const float* __restrict__ fm1,
    const float* __restrict__ fm2, const float* __restrict__ fm3,
    const float* __restrict__ fm4,
    const int* __restrict__ n1, const int* __restrict__ n2,
    float* __restrict__ outp)
{
  int b=blockIdx.y, i=blockIdx.x, t=threadIdx.x;
  size_t obase=((size_t)b*V0+i)*1280;
  int j1=n1[b*V0+i], j2=n2[b*V0+i];
  if(t<128){
    outp[obase+t]      = fm0[(size_t)(b*V0+i)*128+t];
    outp[obase+128+t]  = fm1[(size_t)(b*V0+i)*128+t];
  }
  outp[obase+256+t] = fm2[((size_t)b*V1N+j1)*256+t];
  outp[obase+512+t] = fm3[((size_t)b*V1N+j1)*256+t];
  outp[obase+768+t]     = fm4[((size_t)b*V2N+j2)*512+t];
  outp[obase+768+256+t] = fm4[((size_t)b*V2N+j2)*512+256+t];
}

extern "C" void kernel_launch(void* const* d_in, const int* in_sizes, int n_in,
                              void* d_out, int out_size, void* d_ws, size_t ws_size,
                              hipStream_t stream) {
  const float* x   =(const float*)d_in[0];
  const float* d0  =(const float*)d_in[1];
  const float* w1  =(const float*)d_in[2];
  const float* b1  =(const float*)d_in[3];
  const float* dir1=(const float*)d_in[4];
  const float* g1  =(const float*)d_in[5];
  const float* bb1 =(const float*)d_in[6];
  const float* w2  =(const float*)d_in[7];
  const float* b2  =(const float*)d_in[8];
  const float* dir2=(const float*)d_in[9];
  const float* g2  =(const float*)d_in[10];
  const float* bb2 =(const float*)d_in[11];
  const float* w3  =(const float*)d_in[12];
  const float* b3  =(const float*)d_in[13];
  const float* dir3=(const float*)d_in[14];
  const float* g3  =(const float*)d_in[15];
  const float* bb3 =(const float*)d_in[16];
  const float* w4  =(const float*)d_in[17];
  const float* b4  =(const float*)d_in[18];
  const float* dir4=(const float*)d_in[19];
  const int* perm1 =(const int*)d_in[20];
  const int* perm2 =(const int*)d_in[21];
  float* out=(float*)d_out;

  // ---- workspace layout (floats) ----
  float* w=(float*)d_ws;
  size_t off=0;
  auto alloc=[&](size_t n){ float* p=w+off; off+=n; return p; };
  float* cn0 =alloc(2688);
  float* cn1 =alloc(2688);
  float* cn2 =alloc(5376);
  float* cn3 =alloc(5376);
  float* cn4 =alloc(10752);
  float* dirnx =alloc((size_t)BNUM*V0*30);
  float* dirnv1=alloc((size_t)BNUM*V1N*30);
  float* dirnv2=alloc((size_t)BNUM*V2N*30);
  float* fm0 =alloc((size_t)BNUM*V0*128);
  float* feat=alloc((size_t)BNUM*V0*1024);   // shared by feat1..feat4 (max size)
  float* fm1r=alloc((size_t)BNUM*V0*128);
  float* fm1 =alloc((size_t)BNUM*V0*128);
  float* f1  =alloc((size_t)BNUM*V1N*128);
  float* v1  =alloc((size_t)BNUM*V1N*3);
  float* fm2r=alloc((size_t)BNUM*V1N*256);
  float* fm2 =alloc((size_t)BNUM*V1N*256);
  float* fm3r=alloc((size_t)BNUM*V1N*256);
  float* fm3 =alloc((size_t)BNUM*V1N*256);
  float* f2  =alloc((size_t)BNUM*V2N*256);
  float* v2  =alloc((size_t)BNUM*V2N*3);
  float* fm4 =alloc((size_t)BNUM*V2N*512);
  float* stats=alloc(1280);  // [0,256): L1 sums; [256,768): L2; [768,1280): L3
  int* idx10x =(int*)alloc((size_t)BNUM*V0*10);
  int* idx4p1 =(int*)alloc((size_t)BNUM*V1N*4);
  int* idx10v1=(int*)alloc((size_t)BNUM*V1N*10);
  int* idx4p2 =(int*)alloc((size_t)BNUM*V2N*4);
  int* idx10v2=(int*)alloc((size_t)BNUM*V2N*10);
  int* n1i =(int*)alloc((size_t)BNUM*V0);
  int* n2i =(int*)alloc((size_t)BNUM*V0);

  hipMemsetAsync(stats, 0, 1280*sizeof(float), stream);

  // column-normalized direction banks
  colnorm_k<<<dim3(4),256,0,stream>>>(d0, cn0, 896);
  colnorm_k<<<dim3(4),256,0,stream>>>(dir1, cn1, 896);
  colnorm_k<<<dim3(7),256,0,stream>>>(dir2, cn2, 1792);
  colnorm_k<<<dim3(7),256,0,stream>>>(dir3, cn3, 1792);
  colnorm_k<<<dim3(14),256,0,stream>>>(dir4, cn4, 3584);

  size_t ldsA=(size_t)V0*4 + 256*4 + 256*4 + 64;
  size_t ldsB=(size_t)V1N*4 + 256*4 + 256*4 + 64;
  size_t ldsC=(size_t)V2N*4 + 256*4 + 256*4 + 64;

  // knn10 on x (+dirn)
  knn_k<<<dim3(V0,BNUM),256,ldsA,stream>>>(x, V0, x, V0, nullptr, 10, 1, idx10x, dirnx);

  // fm0 = silu(conv_surface)
  conv_surf_k<<<dim3(V0,BNUM),128,0,stream>>>(dirnx, cn0, fm0);

  // layer 1
  gemm_bias_k<<<dim3(1024/64, (BNUM*V0)/64),256,0,stream>>>(fm0, w1, b1, feat, BNUM*V0, 1024, 128);
  conv_agg_k<<<dim3(V0,BNUM),128,0,stream>>>(feat, V0, 128, 1024, dirnx, idx10x, cn1, 896, fm1r);
  stats_k<<<dim3((BNUM*V0)/64),128,0,stream>>>(fm1r, 64, 128, stats);
  bn_silu_k<<<dim3((BNUM*V0*128)/256),256,0,stream>>>(fm1r, stats, 1.0f/(BNUM*V0), 128, g1, bb1, fm1, BNUM*V0*128);

  // pool at perm1 rows -> f1 ; v1 = x[:,perm1]
  knn_k<<<dim3(V1N,BNUM),256,ldsA,stream>>>(x, V0, x, V0, perm1, 4, 1, idx4p1, nullptr);
  pool_k<<<dim3(V1N,BNUM),128,0,stream>>>(fm1, V0, 128, idx4p1, f1, V1N);
  gather_rows_k<<<dim3(V1N,BNUM),64,0,stream>>>(x, V0, 3, perm1, v1, V1N);

  // knn10 on v1 (+dirn)
  knn_k<<<dim3(V1N,BNUM),256,ldsB,stream>>>(v1, V1N, v1, V1N, nullptr, 10, 1, idx10v1, dirnv1);

  // layer 2
  gemm_bias_k<<<dim3(2048/64, (BNUM*V1N)/64),256,0,stream>>>(f1, w2, b2, feat, BNUM*V1N, 2048, 128);
  conv_agg_k<<<dim3(V1N,BNUM),256,0,stream>>>(feat, V1N, 256, 2048, dirnv1, idx10v1, cn2, 1792, fm2r);
  stats_k<<<dim3((BNUM*V1N)/64),256,0,stream>>>(fm2r, 64, 256, stats+256);
  bn_silu_k<<<dim3((BNUM*V1N*256)/256),256,0,stream>>>(fm2r, stats+256, 1.0f/(BNUM*V1N), 256, g2, bb2, fm2, BNUM*V1N*256);

  // layer 3
  gemm_bias_k<<<dim3(2048/64, (BNUM*V1N)/64),256,0,stream>>>(fm2, w3, b3, feat, BNUM*V1N, 2048, 256);
  conv_agg_k<<<dim3(V1N,BNUM),256,0,stream>>>(feat, V1N, 256, 2048, dirnv1, idx10v1, cn3, 1792, fm3r);
  stats_k<<<dim3((BNUM*V1N)/64),256,0,stream>>>(fm3r, 64, 256, stats+768);
  bn_silu_k<<<dim3((BNUM*V1N*256)/256),256,0,stream>>>(fm3r, stats+768, 1.0f/(BNUM*V1N), 256, g3, bb3, fm3, BNUM*V1N*256);

  // pool at perm2 rows -> f2 ; v2 = v1[:,perm2]
  knn_k<<<dim3(V2N,BNUM),256,ldsB,stream>>>(v1, V1N, v1, V1N, perm2, 4, 1, idx4p2, nullptr);
  pool_k<<<dim3(V2N,BNUM),256,0,stream>>>(fm3, V1N, 256, idx4p2, f2, V2N);
  gather_rows_k<<<dim3(V2N,BNUM),64,0,stream>>>(v1, V1N, 3, perm2, v2, V2N);

  // knn10 on v2 (+dirn)
  knn_k<<<dim3(V2N,BNUM),256,ldsC,stream>>>(v2, V2N, v2, V2N, nullptr, 10, 1, idx10v2, dirnv2);

  // layer 4 (no bn, no silu)
  gemm_bias_k<<<dim3(4096/64, (BNUM*V2N)/64),256,0,stream>>>(f2, w4, b4, feat, BNUM*V2N, 4096, 256);
  conv_agg_k<<<dim3(V2N,BNUM),512,0,stream>>>(feat, V2N, 512, 4096, dirnv2, idx10v2, cn4, 3584, fm4);

  // nearest upsample indices
  knn_k<<<dim3(V0,BNUM),256,ldsB,stream>>>(v1, V1N, x, V0, nullptr, 1, 0, n1i, nullptr);
  knn_k<<<dim3(V0,BNUM),256,ldsC,stream>>>(v2, V2N, x, V0, nullptr, 1, 0, n2i, nullptr);

  // final concat
  concat_k<<<dim3(V0,BNUM),256,0,stream>>>(fm0, fm1, fm2, fm3, fm4, n1i, n2i, out);
}